// Round 3
// baseline (513.801 us; speedup 1.0000x reference)
//
#include <hip/hip_runtime.h>
#include <math.h>

#define D 128

typedef __attribute__((ext_vector_type(8))) short short8v;   // 8 bf16 = 4 VGPR
typedef __attribute__((ext_vector_type(4))) float f32x4;     // MFMA acc

__device__ inline short f2bf(float f) {                      // RNE fp32->bf16
    unsigned u = __float_as_uint(f);
    u += 0x7FFF + ((u >> 16) & 1);
    return (short)(u >> 16);
}
__device__ inline float bf2f(unsigned short s) {
    return __uint_as_float(((unsigned)s) << 16);
}

// ===========================================================================
// Concatenated CSR build for conv (dst in [0,N)) and jump (dst in [N,2N)).
// pairs[] holds conv entries in [0,E) and jump entries in [E,E+EJ).
// ===========================================================================
__global__ void hist_both(const int* __restrict__ dst_e,
                          const int* __restrict__ dst_j,
                          int* __restrict__ cnt, int E, int EJ, int N) {
    int i = blockIdx.x * blockDim.x + threadIdx.x;
    if (i < E) atomicAdd(&cnt[dst_e[i]], 1);
    else if (i < E + EJ) atomicAdd(&cnt[N + dst_j[i - E]], 1);
}

// Block scans 1024 elements (256 thr x 4). Exclusive offsets + block sum.
__global__ void scan1(const int* __restrict__ cnt, int* __restrict__ offs,
                      int* __restrict__ bsum, int M) {
    __shared__ int sh[256];
    int t = threadIdx.x;
    int base = blockIdx.x * 1024 + t * 4;
    int v0 = 0, v1 = 0, v2 = 0, v3 = 0;
    if (base + 0 < M) v0 = cnt[base + 0];
    if (base + 1 < M) v1 = cnt[base + 1];
    if (base + 2 < M) v2 = cnt[base + 2];
    if (base + 3 < M) v3 = cnt[base + 3];
    int tsum = v0 + v1 + v2 + v3;
    sh[t] = tsum;
    __syncthreads();
    for (int off = 1; off < 256; off <<= 1) {
        int x = (t >= off) ? sh[t - off] : 0;
        __syncthreads();
        sh[t] += x;
        __syncthreads();
    }
    int excl = sh[t] - tsum;
    if (base + 0 < M) offs[base + 0] = excl;
    excl += v0;
    if (base + 1 < M) offs[base + 1] = excl;
    excl += v1;
    if (base + 2 < M) offs[base + 2] = excl;
    excl += v2;
    if (base + 3 < M) offs[base + 3] = excl;
    if (t == 255) bsum[blockIdx.x] = sh[255];
}

__global__ void scan2(int* __restrict__ bsum, int NB) {
    __shared__ int sh[256];
    int t = threadIdx.x;
    int v = (t < NB) ? bsum[t] : 0;
    sh[t] = v;
    __syncthreads();
    for (int off = 1; off < 256; off <<= 1) {
        int x = (t >= off) ? sh[t - off] : 0;
        __syncthreads();
        sh[t] += x;
        __syncthreads();
    }
    if (t < NB) bsum[t] = sh[t] - v;
}

__global__ void scan3(int* __restrict__ offs, const int* __restrict__ bsum,
                      int* __restrict__ cur, int M) {
    int i = blockIdx.x * blockDim.x + threadIdx.x;
    if (i < M) {
        int o = offs[i] + bsum[i >> 10];
        offs[i] = o;
        cur[i] = o;
    }
}

__global__ void fill_both(const int* __restrict__ src_e,
                          const int* __restrict__ dst_e,
                          const int* __restrict__ et,
                          const int* __restrict__ src_j,
                          const int* __restrict__ dst_j,
                          const float* __restrict__ ew,
                          int* __restrict__ cur, int2* __restrict__ pairs,
                          int E, int EJ, int N) {
    int i = blockIdx.x * blockDim.x + threadIdx.x;
    if (i < E) {
        int p = atomicAdd(&cur[dst_e[i]], 1);
        pairs[p] = make_int2(src_e[i], et[i]);
    } else if (i < E + EJ) {
        int e = i - E;
        int p = atomicAdd(&cur[N + dst_j[e]], 1);
        pairs[p] = make_int2(src_j[e], __float_as_int(ew[e]));
    }
}

// ===========================================================================
// Weight pack into MFMA B-fragment lane order (bf16), both layers.
// Stacked K: rows 0..127 = W (agg path), 128..255 = Wl (x path).
// ===========================================================================
__global__ void pack_w(const float* __restrict__ W1, const float* __restrict__ Wl1,
                       const float* __restrict__ W2, const float* __restrict__ Wl2,
                       short* __restrict__ B1, short* __restrict__ B2) {
    int lane = threadIdx.x;          // 64
    int tile = blockIdx.x & 63;      // tn = tile>>3, tk = tile&7
    const float* W  = (blockIdx.x < 64) ? W1 : W2;
    const float* Wl = (blockIdx.x < 64) ? Wl1 : Wl2;
    short* Bpk      = (blockIdx.x < 64) ? B1 : B2;
    int tn = tile >> 3, tk = tile & 7;
    int n = tn * 16 + (lane & 15);
    int k0 = tk * 32 + (lane >> 4) * 8;
    short* o = Bpk + ((size_t)tile * 64 + lane) * 8;
#pragma unroll
    for (int j = 0; j < 8; j++) {
        int k = k0 + j;
        float f = (k < D) ? W[(size_t)k * D + n] : Wl[(size_t)(k - D) * D + n];
        o[j] = f2bf(f);
    }
}

// rel_emb (fp32) -> bf16 copies, both layers in one launch.
__global__ void cvt_rel(const float* __restrict__ r1, const float* __restrict__ r2,
                        short* __restrict__ o1, short* __restrict__ o2, int RD) {
    int i = blockIdx.x * blockDim.x + threadIdx.x;   // one thread per 4 elems
    int half = RD >> 2;
    if (i >= 2 * half) return;
    const float* src = (i < half) ? r1 : r2;
    short* dst = (i < half) ? o1 : o2;
    int j = (i < half) ? i : i - half;
    float4 v = *(const float4*)(src + (size_t)j * 4);
    short4 o;
    o.x = f2bf(v.x); o.y = f2bf(v.y); o.z = f2bf(v.z); o.w = f2bf(v.w);
    *(short4*)(dst + (size_t)j * 4) = o;
}

// emb -> Abf1 x-half (bf16); also change -> out passthrough copy.
__global__ void cvt_emb_copy(const float* __restrict__ emb,
                             const float* __restrict__ change,
                             short* __restrict__ Abf,
                             float* __restrict__ out, int N) {
    int i = blockIdx.x * blockDim.x + threadIdx.x;   // one thread per 4 elems
    int row = i >> 5;
    int c4 = (i & 31) * 4;
    if (row >= N) return;
    float4 v = *(const float4*)(emb + (size_t)row * D + c4);
    short4 o;
    o.x = f2bf(v.x); o.y = f2bf(v.y); o.z = f2bf(v.z); o.w = f2bf(v.w);
    *(short4*)(Abf + (size_t)row * 256 + 128 + c4) = o;
    float4 ch = *(const float4*)(change + (size_t)row * D + c4);
    *(float4*)(out + (size_t)row * D + c4) = ch;
}

// ===========================================================================
// Layer-1 gather: one wave per node, split into FOUR 16-lane groups, each
// handling a different edge per trip (4 edges/trip + 1-deep prefetch = up to
// 8 edges in flight). Each lane loads ushort8 (16 B) so 16 lanes cover one
// full D=128 bf16 row. Tail branchless (clamp + mask). Cross-group combine:
// shfl_xor(16) + shfl_xor(32). Group 0 writes agg (cols 0..127).
// ===========================================================================
__global__ void gather_conv(short* __restrict__ Abf,
                            const short* __restrict__ relb,
                            const int* __restrict__ offs,
                            const int* __restrict__ cnt,
                            const int2* __restrict__ pairs, int N) {
    int node = blockIdx.x * 4 + (threadIdx.x >> 6);
    if (node >= N) return;
    int lane = threadIdx.x & 63;
    int h = lane >> 4;               // group 0..3: edge index mod 4
    int c = (lane & 15) * 8;         // 8 cols per lane
    int beg = offs[node], num = cnt[node];
    float acc[8];
#pragma unroll
    for (int j = 0; j < 8; j++) acc[j] = 0.f;
    if (num > 0) {
        int e0 = (h < num) ? h : (num - 1);
        int2 pe = pairs[beg + e0];
        short8v xv = *(const short8v*)(Abf + (size_t)pe.x * 256 + 128 + c);
        short8v rv = *(const short8v*)(relb + (size_t)pe.y * D + c);
        float mk = (h < num) ? 1.f : 0.f;
        for (int i = 4; i < num; i += 4) {
            int ei = i + h;
            int e2 = (ei < num) ? ei : (num - 1);
            int2 pe2 = pairs[beg + e2];
            short8v xv2 = *(const short8v*)(Abf + (size_t)pe2.x * 256 + 128 + c);
            short8v rv2 = *(const short8v*)(relb + (size_t)pe2.y * D + c);
            float mk2 = (ei < num) ? 1.f : 0.f;
#pragma unroll
            for (int j = 0; j < 8; j++)
                acc[j] += mk * bf2f((unsigned short)xv[j]) * bf2f((unsigned short)rv[j]);
            xv = xv2; rv = rv2; mk = mk2;
        }
#pragma unroll
        for (int j = 0; j < 8; j++)
            acc[j] += mk * bf2f((unsigned short)xv[j]) * bf2f((unsigned short)rv[j]);
#pragma unroll
        for (int j = 0; j < 8; j++) {
            acc[j] += __shfl_xor(acc[j], 16);
            acc[j] += __shfl_xor(acc[j], 32);
        }
    }
    if (h == 0) {
        float dinv = 1.0f / fmaxf((float)num, 1.0f);
        short8v o;
#pragma unroll
        for (int j = 0; j < 8; j++) o[j] = f2bf(acc[j] * dinv);
        *(short8v*)(Abf + (size_t)node * 256 + c) = o;
    }
}

// ===========================================================================
// Phase-2 gathers merged: nodes [0,N) = layer-2 conv on Abf2 (h1 bf16);
// nodes [N,2N) = jump diffusion from Abf1 x-half (emb bf16) -> dch fp32.
// Same 4-group 16-lane structure as gather_conv.
// ===========================================================================
__global__ void gather_phase2(short* __restrict__ Abf2,
                              const short* __restrict__ Abf1,
                              const short* __restrict__ relb,
                              const float* __restrict__ jwp,
                              const int* __restrict__ offs,
                              const int* __restrict__ cnt,
                              const int2* __restrict__ pairs,
                              float* __restrict__ dch, int N) {
    int g = blockIdx.x * 4 + (threadIdx.x >> 6);
    int lane = threadIdx.x & 63;
    int h = lane >> 4;
    int c = (lane & 15) * 8;
    if (g < N) {
        int beg = offs[g], num = cnt[g];
        float acc[8];
#pragma unroll
        for (int j = 0; j < 8; j++) acc[j] = 0.f;
        if (num > 0) {
            int e0 = (h < num) ? h : (num - 1);
            int2 pe = pairs[beg + e0];
            short8v xv = *(const short8v*)(Abf2 + (size_t)pe.x * 256 + 128 + c);
            short8v rv = *(const short8v*)(relb + (size_t)pe.y * D + c);
            float mk = (h < num) ? 1.f : 0.f;
            for (int i = 4; i < num; i += 4) {
                int ei = i + h;
                int e2 = (ei < num) ? ei : (num - 1);
                int2 pe2 = pairs[beg + e2];
                short8v xv2 = *(const short8v*)(Abf2 + (size_t)pe2.x * 256 + 128 + c);
                short8v rv2 = *(const short8v*)(relb + (size_t)pe2.y * D + c);
                float mk2 = (ei < num) ? 1.f : 0.f;
#pragma unroll
                for (int j = 0; j < 8; j++)
                    acc[j] += mk * bf2f((unsigned short)xv[j]) * bf2f((unsigned short)rv[j]);
                xv = xv2; rv = rv2; mk = mk2;
            }
#pragma unroll
            for (int j = 0; j < 8; j++)
                acc[j] += mk * bf2f((unsigned short)xv[j]) * bf2f((unsigned short)rv[j]);
#pragma unroll
            for (int j = 0; j < 8; j++) {
                acc[j] += __shfl_xor(acc[j], 16);
                acc[j] += __shfl_xor(acc[j], 32);
            }
        }
        if (h == 0) {
            float dinv = 1.0f / fmaxf((float)num, 1.0f);
            short8v o;
#pragma unroll
            for (int j = 0; j < 8; j++) o[j] = f2bf(acc[j] * dinv);
            *(short8v*)(Abf2 + (size_t)g * 256 + c) = o;
        }
    } else if (g < 2 * N) {
        int node = g - N;
        int beg = offs[N + node], num = cnt[N + node];
        float acc[8];
#pragma unroll
        for (int j = 0; j < 8; j++) acc[j] = 0.f;
        if (num > 0) {
            int e0 = (h < num) ? h : (num - 1);
            int2 pe = pairs[beg + e0];
            short8v xv = *(const short8v*)(Abf1 + (size_t)pe.x * 256 + 128 + c);
            float wgt = ((h < num) ? 1.f : 0.f) * __int_as_float(pe.y);
            for (int i = 4; i < num; i += 4) {
                int ei = i + h;
                int e2 = (ei < num) ? ei : (num - 1);
                int2 pe2 = pairs[beg + e2];
                short8v xv2 = *(const short8v*)(Abf1 + (size_t)pe2.x * 256 + 128 + c);
                float wgt2 = ((ei < num) ? 1.f : 0.f) * __int_as_float(pe2.y);
#pragma unroll
                for (int j = 0; j < 8; j++)
                    acc[j] += wgt * bf2f((unsigned short)xv[j]);
                xv = xv2; wgt = wgt2;
            }
#pragma unroll
            for (int j = 0; j < 8; j++)
                acc[j] += wgt * bf2f((unsigned short)xv[j]);
#pragma unroll
            for (int j = 0; j < 8; j++) {
                acc[j] += __shfl_xor(acc[j], 16);
                acc[j] += __shfl_xor(acc[j], 32);
            }
        }
        if (h == 0) {
            float jw = jwp[0];
            float* drow = dch + (size_t)node * D + c;
            *(float4*)(drow + 0) = make_float4(jw * acc[0], jw * acc[1],
                                               jw * acc[2], jw * acc[3]);
            *(float4*)(drow + 4) = make_float4(jw * acc[4], jw * acc[5],
                                               jw * acc[6], jw * acc[7]);
        }
    }
}

// ===========================================================================
// MFMA GEMM: C = Abf[N][256] @ Bpk(256x128); o = bf16(x) + res*tanh(C).
// Layer 1: o -> outb x-half (bf16).  Layer 2: o + addin -> outf (fp32).
// Block: 256 thr = 4 waves, tile 64 rows x 128 cols; no LDS, no barriers.
// ===========================================================================
__launch_bounds__(256)
__global__ void mfma_gemm(const short* __restrict__ Abf,
                          const short* __restrict__ Bpk,
                          const float* __restrict__ resp,
                          short* __restrict__ outb,        // nullable
                          const float* __restrict__ addin, // nullable
                          float* __restrict__ outf,        // nullable
                          int N) {
    int w = threadIdx.x >> 6;
    int lane = threadIdx.x & 63;
    int rb = (w & 1) * 32;
    int cb = (w >> 1) * 64;
    int row0 = blockIdx.x * 64;
    int m = lane & 15, quad = lane >> 4;

    f32x4 acc[2][4];
#pragma unroll
    for (int rt = 0; rt < 2; rt++)
#pragma unroll
        for (int ct = 0; ct < 4; ct++) acc[rt][ct] = (f32x4)(0.f);

    const short* arow0 = Abf + (size_t)(row0 + rb + m) * 256 + quad * 8;
    const short* arow1 = arow0 + 16 * 256;
    const short* bbase = Bpk + (((size_t)(cb >> 4)) * 8 * 64 + lane) * 8;

#pragma unroll
    for (int kt = 0; kt < 8; kt++) {
        short8v a0 = *(const short8v*)(arow0 + kt * 32);
        short8v a1 = *(const short8v*)(arow1 + kt * 32);
        short8v b[4];
#pragma unroll
        for (int ct = 0; ct < 4; ct++)
            b[ct] = *(const short8v*)(bbase + ((size_t)(ct * 8 + kt)) * 64 * 8);
#pragma unroll
        for (int ct = 0; ct < 4; ct++) {
            acc[0][ct] = __builtin_amdgcn_mfma_f32_16x16x32_bf16(a0, b[ct],
                                                                 acc[0][ct], 0, 0, 0);
            acc[1][ct] = __builtin_amdgcn_mfma_f32_16x16x32_bf16(a1, b[ct],
                                                                 acc[1][ct], 0, 0, 0);
        }
    }

    float res = resp[0];
#pragma unroll
    for (int rt = 0; rt < 2; rt++) {
#pragma unroll
        for (int ct = 0; ct < 4; ct++) {
            int colg = cb + ct * 16 + m;
#pragma unroll
            for (int r = 0; r < 4; r++) {
                int rowg = row0 + rb + rt * 16 + quad * 4 + r;
                if (rowg >= N) continue;
                float xr = bf2f((unsigned short)Abf[(size_t)rowg * 256 + 128 + colg]);
                float o = xr + res * tanhf(acc[rt][ct][r]);
                if (outb != nullptr) {
                    outb[(size_t)rowg * 256 + 128 + colg] = f2bf(o);
                } else {
                    size_t idx = (size_t)rowg * D + colg;
                    outf[idx] = o + addin[idx];
                }
            }
        }
    }
}

extern "C" void kernel_launch(void* const* d_in, const int* in_sizes, int n_in,
                              void* d_out, int out_size, void* d_ws, size_t ws_size,
                              hipStream_t stream) {
    const float* emb    = (const float*)d_in[0];
    const float* change = (const float*)d_in[1];
    const float* W1     = (const float*)d_in[2];
    const float* Wl1    = (const float*)d_in[3];
    const float* rel1   = (const float*)d_in[4];
    const float* W2     = (const float*)d_in[5];
    const float* Wl2    = (const float*)d_in[6];
    const float* rel2   = (const float*)d_in[7];
    const float* res    = (const float*)d_in[8];
    const float* jw     = (const float*)d_in[9];
    const float* ewj    = (const float*)d_in[10];
    const int*   eidx   = (const int*)d_in[11];
    const int*   etype  = (const int*)d_in[12];
    const int*   ejmp   = (const int*)d_in[13];

    const int ND = in_sizes[0];
    const int N  = ND / D;
    const int E  = in_sizes[12];
    const int EJ = in_sizes[10];
    const int RD = in_sizes[4];              // R*D elements per rel matrix
    const int NP = ((N + 63) / 64) * 64;     // row-padded for 64-row GEMM tiles
    const int M  = 2 * N;                    // concatenated CSR counters

    float* out = (float*)d_out;          // change passthrough
    float* dch = out + (size_t)ND;       // dchange

    // workspace layout (16B-aligned chunks)
    char* w = (char*)d_ws;
    short* Abf1  = (short*)w;                  w += (size_t)NP * 256 * 2;
    short* Abf2  = (short*)w;                  w += (size_t)NP * 256 * 2;
    short* Bpk1  = (short*)w;                  w += (size_t)64 * 64 * 8 * 2;
    short* Bpk2  = (short*)w;                  w += (size_t)64 * 64 * 8 * 2;
    short* relb1 = (short*)w;                  w += (size_t)RD * 2;
    short* relb2 = (short*)w;                  w += (size_t)RD * 2;
    int* cnt     = (int*)w;                    w += (size_t)M * 4;
    int* offs    = (int*)w;                    w += (size_t)M * 4;
    int* cur     = (int*)w;                    w += (size_t)M * 4;
    int* bsum    = (int*)w;                    w += 256 * 4;
    int2* pairs  = (int2*)w;                   w += (size_t)(E + EJ) * 8;

    const int T = 256;
    const int NB2 = (M + 1023) / 1024;
    const int EB  = (E + EJ + T - 1) / T;

    hipMemsetAsync(cnt, 0, (size_t)M * sizeof(int), stream);

    // ---- concatenated CSR build (conv + jump) ----
    hist_both<<<EB, T, 0, stream>>>(eidx + E, ejmp + EJ, cnt, E, EJ, N);
    scan1<<<NB2, 256, 0, stream>>>(cnt, offs, bsum, M);
    scan2<<<1, 256, 0, stream>>>(bsum, NB2);
    scan3<<<(M + T - 1) / T, T, 0, stream>>>(offs, bsum, cur, M);
    fill_both<<<EB, T, 0, stream>>>(eidx, eidx + E, etype, ejmp, ejmp + EJ, ewj,
                                    cur, pairs, E, EJ, N);

    // ---- weight packs (both layers) + rel -> bf16 ----
    pack_w<<<128, 64, 0, stream>>>(W1, Wl1, W2, Wl2, Bpk1, Bpk2);
    cvt_rel<<<(RD / 2 + T - 1) / T, T, 0, stream>>>(rel1, rel2, relb1, relb2, RD);

    // ---- emb -> bf16, change -> out ----
    cvt_emb_copy<<<(N * 32 + T - 1) / T, T, 0, stream>>>(emb, change, Abf1, out, N);

    int gatherB  = (N + 3) / 4;
    int gather2B = (M + 3) / 4;
    int gemmB    = NP / 64;

    // ---- layer 1: gather + GEMM (h1 -> Abf2 x-half bf16) ----
    gather_conv<<<gatherB, 256, 0, stream>>>(Abf1, relb1, offs, cnt, pairs, N);
    mfma_gemm<<<gemmB, 256, 0, stream>>>(Abf1, Bpk1, res, Abf2, nullptr, nullptr, N);

    // ---- layer-2 conv gather + jump gather (merged) ----
    gather_phase2<<<gather2B, 256, 0, stream>>>(Abf2, Abf1, relb2, jw, offs, cnt,
                                                pairs, dch, N);

    // ---- layer 2 GEMM: dch = h1 + res*tanh(...) + jump ----
    mfma_gemm<<<gemmB, 256, 0, stream>>>(Abf2, Bpk2, res, nullptr, dch, dch, N);
}